// Round 3
// baseline (7773.914 us; speedup 1.0000x reference)
//
#include <hip/hip_runtime.h>
#include <stdint.h>

#define DD 256
#define NEDGE 300000
#define NNODE 100000
#define NLAY 9
#define LN_EPS 1e-5f

typedef __attribute__((ext_vector_type(8))) short bf16x8;
typedef __attribute__((ext_vector_type(4))) short s16x4;
typedef __attribute__((ext_vector_type(4))) float f32x4;
typedef __attribute__((ext_vector_type(4))) int i32x4;

static __device__ __forceinline__ short f2bf(float f) {
  union { float f; uint32_t u; } v; v.f = f;
  uint32_t r = (v.u + 0x7FFFu + ((v.u >> 16) & 1u)) >> 16;
  return (short)(uint16_t)r;
}
static __device__ __forceinline__ float bf2f(short s) {
  union { uint32_t u; float f; } v; v.u = ((uint32_t)(uint16_t)s) << 16;
  return v.f;
}

static __device__ __forceinline__ void gld16(const void* g, void* l) {
  __builtin_amdgcn_global_load_lds((const __attribute__((address_space(1))) void*)g,
                                   (__attribute__((address_space(3))) void*)l, 16, 0, 0);
}

// ---------------------------------------------------------------------------
// Persistent fused MLP. 256 thr = 4 waves; wave owns 64 output cols.
// W1+W2 in REGISTERS (loaded once per block). Block grid-strides row-tiles
// of 64. A staged one full tile ahead via global_load_lds (dbuf 2x32KB,
// XOR-swizzled via pre-swizzled global source). No barriers inside GEMMs.
// LDS: abuf0 @0, abuf1 @32768, hidden @65536 (32KB), redbuf @98304 (2KB).
// ---------------------------------------------------------------------------
template<bool A_BF16, bool NODE>
__global__ __launch_bounds__(256, 1) void mlp_kernel(
    const void* __restrict__ Ain, const int* __restrict__ rowmap,
    const short* __restrict__ W1, const short* __restrict__ W2,
    const float* __restrict__ B1, const float* __restrict__ B2,
    const float* __restrict__ LG, const float* __restrict__ LB,
    short* __restrict__ OutB, float* __restrict__ OutF,
    const float* __restrict__ Resid, short* __restrict__ XbOut, int M) {
  extern __shared__ char smem[];
  short* hidden = (short*)(smem + 65536);
  float* redbuf = (float*)(smem + 98304);
  const int tid = threadIdx.x;
  const int lane = tid & 63;
  const int wv = tid >> 6;
  const int l15 = lane & 15, lq = lane >> 4;
  const int cbase = wv * 64;
  const int ntiles = (M + 63) >> 6;

  // ---- W1, W2 into registers (once per block) ----
  bf16x8 wf1[8][4], wf2[8][4];
#pragma unroll
  for (int kk = 0; kk < 8; ++kk)
#pragma unroll
    for (int ni = 0; ni < 4; ++ni) {
      const int col = cbase + ni * 16 + l15;
      wf1[kk][ni] = *(const bf16x8*)(W1 + (size_t)col * DD + kk * 32 + lq * 8);
      wf2[kk][ni] = *(const bf16x8*)(W2 + (size_t)col * DD + kk * 32 + lq * 8);
    }
  float b1v[4], b2v[4], gv[4], bvv[4];
#pragma unroll
  for (int ni = 0; ni < 4; ++ni) {
    const int c = cbase + ni * 16 + l15;
    b1v[ni] = B1[c]; b2v[ni] = B2[c]; gv[ni] = LG[c]; bvv[ni] = LB[c];
  }

  // DMA-stage one 64-row A tile (bf16) into abuf[pb2]; pre-swizzled source.
  auto stageA = [&](int tt, int pb2) {
    if constexpr (A_BF16) {
      const int R0 = wv * 16;
      char* base = smem + pb2 * 32768 + R0 * 512;
      const short* A = (const short*)Ain;
#pragma unroll
      for (int i = 0; i < 8; ++i) {
        const int rl = R0 + i * 2 + (lane >> 5);
        const int gr = min(tt * 64 + rl, M - 1);
        const int o = (lane & 31) ^ (rl & 7);
        gld16(A + (size_t)gr * DD + o * 8, base + i * 1024);
      }
    }
  };

  f32x4 acc[4][4];
  if (blockIdx.x < ntiles) stageA(blockIdx.x, 0);
  __syncthreads();

  int pb = 0;
  for (int t = blockIdx.x; t < ntiles; t += gridDim.x, pb ^= 1) {
    const int r0 = t * 64;
    const int tnext = t + gridDim.x;
    if (tnext < ntiles) stageA(tnext, pb ^ 1);

#pragma unroll
    for (int mi = 0; mi < 4; ++mi)
#pragma unroll
      for (int ni = 0; ni < 4; ++ni) acc[mi][ni] = (f32x4){0.f, 0.f, 0.f, 0.f};

    // ---------------- GEMM1: h = relu(A @ W1^T + b1), no barriers ----------
    const short* Ash = (const short*)(smem + pb * 32768);
#pragma unroll
    for (int kk = 0; kk < 8; ++kk) {
      bf16x8 a[4];
#pragma unroll
      for (int mi = 0; mi < 4; ++mi) {
        if (A_BF16) {
          a[mi] = *(const bf16x8*)(Ash + (mi * 16 + l15) * 256 +
                                   (((kk * 4 + lq) ^ (l15 & 7)) << 3));
        } else {
          const int ar = min(r0 + mi * 16 + l15, M - 1);
          const float* af = (const float*)Ain + (size_t)(rowmap ? rowmap[ar] : ar) * DD;
          const f32x4 u0 = *(const f32x4*)(af + kk * 32 + lq * 8);
          const f32x4 u1 = *(const f32x4*)(af + kk * 32 + lq * 8 + 4);
#pragma unroll
          for (int j = 0; j < 4; ++j) { a[mi][j] = f2bf(u0[j]); a[mi][j + 4] = f2bf(u1[j]); }
        }
      }
#pragma unroll
      for (int ni = 0; ni < 4; ++ni)
#pragma unroll
        for (int mi = 0; mi < 4; ++mi)
          acc[mi][ni] = __builtin_amdgcn_mfma_f32_16x16x32_bf16(a[mi], wf1[kk][ni], acc[mi][ni], 0, 0, 0);
    }
    // epilogue 1: bias + relu -> hidden (granule-swizzled bf16)
#pragma unroll
    for (int ni = 0; ni < 4; ++ni) {
      const int c = cbase + ni * 16 + l15;
#pragma unroll
      for (int mi = 0; mi < 4; ++mi)
#pragma unroll
        for (int i = 0; i < 4; ++i) {
          const int row = mi * 16 + lq * 4 + i;
          hidden[row * DD + ((((c >> 3) ^ (row & 7))) << 3) + (c & 7)] =
              f2bf(fmaxf(acc[mi][ni][i] + b1v[ni], 0.f));
          acc[mi][ni][i] = 0.f;
        }
    }
    __syncthreads();  // B1: hidden ready (also drains A-DMA for next tile)

    // ---------------- GEMM2: y = h @ W2^T, no barriers ---------------------
#pragma unroll
    for (int kk = 0; kk < 8; ++kk) {
      bf16x8 a[4];
#pragma unroll
      for (int mi = 0; mi < 4; ++mi) {
        const int hr = mi * 16 + l15;
        a[mi] = *(const bf16x8*)(hidden + hr * DD + (((kk * 4 + lq) ^ (hr & 7)) << 3));
      }
#pragma unroll
      for (int ni = 0; ni < 4; ++ni)
#pragma unroll
        for (int mi = 0; mi < 4; ++mi)
          acc[mi][ni] = __builtin_amdgcn_mfma_f32_16x16x32_bf16(a[mi], wf2[kk][ni], acc[mi][ni], 0, 0, 0);
    }
    // ---------------- LayerNorm ----------------
    float mean_[4][4], inv_[4][4];
#pragma unroll
    for (int mi = 0; mi < 4; ++mi)
#pragma unroll
      for (int i = 0; i < 4; ++i) {
        float s1 = 0.f, s2 = 0.f;
#pragma unroll
        for (int ni = 0; ni < 4; ++ni) {
          const float v = acc[mi][ni][i] + b2v[ni];
          s1 += v; s2 += v * v;
        }
#pragma unroll
        for (int off = 1; off < 16; off <<= 1) {
          s1 += __shfl_xor(s1, off);
          s2 += __shfl_xor(s2, off);
        }
        mean_[mi][i] = s1; inv_[mi][i] = s2;
      }
    if (l15 == 0) {
#pragma unroll
      for (int mi = 0; mi < 4; ++mi)
#pragma unroll
        for (int i = 0; i < 4; ++i) {
          const int row = mi * 16 + lq * 4 + i;
          redbuf[(row * 4 + wv) * 2 + 0] = mean_[mi][i];
          redbuf[(row * 4 + wv) * 2 + 1] = inv_[mi][i];
        }
    }
    __syncthreads();  // B2: redbuf ready; hidden reads done
#pragma unroll
    for (int mi = 0; mi < 4; ++mi)
#pragma unroll
      for (int i = 0; i < 4; ++i) {
        const int row = mi * 16 + lq * 4 + i;
        float t1 = 0.f, t2 = 0.f;
#pragma unroll
        for (int w = 0; w < 4; ++w) {
          t1 += redbuf[(row * 4 + w) * 2 + 0];
          t2 += redbuf[(row * 4 + w) * 2 + 1];
        }
        const float mean = t1 * (1.f / 256.f);
        const float var = t2 * (1.f / 256.f) - mean * mean;
        mean_[mi][i] = mean;
        inv_[mi][i] = rsqrtf(var + LN_EPS);
      }

    if (NODE) {
      // two passes of 128 cols through the 32KB hidden region (f32)
      float* ob = (float*)(smem + 65536);
#pragma unroll
      for (int h = 0; h < 2; ++h) {
        if ((cbase >> 7) == h) {
#pragma unroll
          for (int ni = 0; ni < 4; ++ni) {
            const int cl = cbase - h * 128 + ni * 16 + l15;
#pragma unroll
            for (int mi = 0; mi < 4; ++mi)
#pragma unroll
              for (int i = 0; i < 4; ++i) {
                const int row = mi * 16 + lq * 4 + i;
                const float y = (acc[mi][ni][i] + b2v[ni] - mean_[mi][i]) * inv_[mi][i] * gv[ni] + bvv[ni];
                ob[row * 128 + (((cl >> 2) ^ (row & 7)) << 2) + (cl & 3)] = y;
              }
          }
        }
        __syncthreads();  // ob(h) ready
#pragma unroll
        for (int j = 0; j < 8; ++j) {
          const int gg = tid + 256 * j;
          const int row = gg >> 5, Lc = gg & 31;
          const int grow = r0 + row;
          if (grow < M) {
            f32x4 v = *(const f32x4*)(ob + row * 128 + ((Lc ^ (row & 7)) << 2));
            const f32x4 xr = *(const f32x4*)(Resid + (size_t)grow * DD + h * 128 + Lc * 4);
            v = v + xr;
            *(f32x4*)(OutF + (size_t)grow * DD + h * 128 + Lc * 4) = v;
            s16x4 o; o.x = f2bf(v.x); o.y = f2bf(v.y); o.z = f2bf(v.z); o.w = f2bf(v.w);
            *(s16x4*)(XbOut + (size_t)grow * DD + h * 128 + Lc * 4) = o;
          }
        }
        __syncthreads();  // ob reads done before next pass / next tile
      }
    } else {
      short* ob = hidden;  // reuse hidden region, same swizzle
#pragma unroll
      for (int ni = 0; ni < 4; ++ni) {
        const int c = cbase + ni * 16 + l15;
#pragma unroll
        for (int mi = 0; mi < 4; ++mi)
#pragma unroll
          for (int i = 0; i < 4; ++i) {
            const int row = mi * 16 + lq * 4 + i;
            const float y = (acc[mi][ni][i] + b2v[ni] - mean_[mi][i]) * inv_[mi][i] * gv[ni] + bvv[ni];
            ob[row * DD + (((c >> 3) ^ (row & 7)) << 3) + (c & 7)] = f2bf(y);
          }
      }
      __syncthreads();  // ob ready
#pragma unroll
      for (int j = 0; j < 8; ++j) {
        const int gg = tid + 256 * j;
        const int row = gg >> 5, Lg = gg & 31;
        const int grow = r0 + row;
        if (grow < M) {
          const i32x4 v = *(const i32x4*)(ob + row * DD + ((Lg ^ (row & 7)) << 3));
          *(i32x4*)(OutB + (size_t)grow * DD + Lg * 8) = v;
        }
      }
      __syncthreads();  // ob reads done before next tile writes hidden
    }
  }
}

// ----------------------- aggregation: wave per node, CSR-sorted efeat ------
__global__ __launch_bounds__(256) void aggregate_kernel(
    const short* __restrict__ xb, const short* __restrict__ efs,
    const int* __restrict__ offs, const int* __restrict__ ssrc,
    short* __restrict__ aggr) {
  const int w = (blockIdx.x * blockDim.x + threadIdx.x) >> 6;
  if (w >= NNODE) return;
  const int lane = threadIdx.x & 63;
  const int beg = offs[w], end = offs[w + 1];
  float s0 = 0.f, s1 = 0.f, s2 = 0.f, s3 = 0.f;
  int p = beg;
  for (; p + 3 < end; p += 4) {
    const int a0 = ssrc[p], a1 = ssrc[p + 1], a2 = ssrc[p + 2], a3 = ssrc[p + 3];
    const s16x4 e0 = *(const s16x4*)(efs + (size_t)p * DD + lane * 4);
    const s16x4 e1 = *(const s16x4*)(efs + (size_t)(p + 1) * DD + lane * 4);
    const s16x4 e2 = *(const s16x4*)(efs + (size_t)(p + 2) * DD + lane * 4);
    const s16x4 e3 = *(const s16x4*)(efs + (size_t)(p + 3) * DD + lane * 4);
    const s16x4 x0 = *(const s16x4*)(xb + (size_t)a0 * DD + lane * 4);
    const s16x4 x1 = *(const s16x4*)(xb + (size_t)a1 * DD + lane * 4);
    const s16x4 x2 = *(const s16x4*)(xb + (size_t)a2 * DD + lane * 4);
    const s16x4 x3 = *(const s16x4*)(xb + (size_t)a3 * DD + lane * 4);
    s0 += bf2f(e0.x) + bf2f(x0.x) + bf2f(e1.x) + bf2f(x1.x) +
          bf2f(e2.x) + bf2f(x2.x) + bf2f(e3.x) + bf2f(x3.x);
    s1 += bf2f(e0.y) + bf2f(x0.y) + bf2f(e1.y) + bf2f(x1.y) +
          bf2f(e2.y) + bf2f(x2.y) + bf2f(e3.y) + bf2f(x3.y);
    s2 += bf2f(e0.z) + bf2f(x0.z) + bf2f(e1.z) + bf2f(x1.z) +
          bf2f(e2.z) + bf2f(x2.z) + bf2f(e3.z) + bf2f(x3.z);
    s3 += bf2f(e0.w) + bf2f(x0.w) + bf2f(e1.w) + bf2f(x1.w) +
          bf2f(e2.w) + bf2f(x2.w) + bf2f(e3.w) + bf2f(x3.w);
  }
  for (; p < end; ++p) {
    const s16x4 ev = *(const s16x4*)(efs + (size_t)p * DD + lane * 4);
    const s16x4 xv = *(const s16x4*)(xb + (size_t)ssrc[p] * DD + lane * 4);
    s0 += bf2f(ev.x) + bf2f(xv.x);
    s1 += bf2f(ev.y) + bf2f(xv.y);
    s2 += bf2f(ev.z) + bf2f(xv.z);
    s3 += bf2f(ev.w) + bf2f(xv.w);
  }
  s16x4 o; o.x = f2bf(s0); o.y = f2bf(s1); o.z = f2bf(s2); o.w = f2bf(s3);
  *(s16x4*)(aggr + (size_t)w * DD + lane * 4) = o;
}

__global__ void count_kernel(const int* __restrict__ tgt, int* __restrict__ deg) {
  const int e = blockIdx.x * 256 + threadIdx.x;
  if (e < NEDGE) atomicAdd(&deg[tgt[e]], 1);
}

__global__ __launch_bounds__(1024) void scan_kernel(
    const int* __restrict__ deg, int* __restrict__ offs, int* __restrict__ cur) {
  __shared__ int part[1024];
  const int t = threadIdx.x;
  const int CH = 98;  // 1024*98 >= 100000
  const int base = t * CH;
  int s = 0;
  for (int i = 0; i < CH; ++i) {
    const int idx = base + i;
    if (idx < NNODE) s += deg[idx];
  }
  part[t] = s;
  __syncthreads();
  for (int off = 1; off < 1024; off <<= 1) {
    const int v = (t >= off) ? part[t - off] : 0;
    __syncthreads();
    part[t] += v;
    __syncthreads();
  }
  int run = (t > 0) ? part[t - 1] : 0;  // exclusive prefix
  for (int i = 0; i < CH; ++i) {
    const int idx = base + i;
    if (idx < NNODE) {
      offs[idx] = run;
      cur[idx] = run;
      run += deg[idx];
    }
  }
  if (t == 1023) offs[NNODE] = part[1023];
}

__global__ void fill_kernel(const int* __restrict__ src, const int* __restrict__ tgt,
                            int* cur, int* seid, int* ssrc) {
  const int e = blockIdx.x * 256 + threadIdx.x;
  if (e < NEDGE) {
    const int t = tgt[e];
    const int p = atomicAdd(&cur[t], 1);
    seid[p] = e;
    ssrc[p] = src[e];
  }
}

__global__ void cvt4_kernel(const float* __restrict__ src, short* __restrict__ dst, int n4) {
  for (int i = blockIdx.x * blockDim.x + threadIdx.x; i < n4; i += gridDim.x * blockDim.x) {
    const f32x4 v = ((const f32x4*)src)[i];
    s16x4 o;
    o.x = f2bf(v.x); o.y = f2bf(v.y); o.z = f2bf(v.z); o.w = f2bf(v.w);
    ((s16x4*)dst)[i] = o;
  }
}

// gather rows by perm and convert f32 -> bf16 (wave per row)
__global__ __launch_bounds__(256) void gather_cvt_kernel(
    const float* __restrict__ src, const int* __restrict__ perm,
    short* __restrict__ dst, int n) {
  const int w = (blockIdx.x * blockDim.x + threadIdx.x) >> 6;
  if (w >= n) return;
  const int lane = threadIdx.x & 63;
  const f32x4 v = *(const f32x4*)(src + (size_t)perm[w] * DD + lane * 4);
  s16x4 o; o.x = f2bf(v.x); o.y = f2bf(v.y); o.z = f2bf(v.z); o.w = f2bf(v.w);
  *(s16x4*)(dst + (size_t)w * DD + lane * 4) = o;
}

// ---------------------------------------------------------------------------
extern "C" void kernel_launch(void* const* d_in, const int* in_sizes, int n_in,
                              void* d_out, int out_size, void* d_ws, size_t ws_size,
                              hipStream_t stream) {
  const float* x_in = (const float*)d_in[0];
  const float* ea_f = (const float*)d_in[1];
  const float* e1w = (const float*)d_in[2];
  const float* e1b = (const float*)d_in[3];
  const float* e2w = (const float*)d_in[4];
  const float* e2b = (const float*)d_in[5];
  const float* elg = (const float*)d_in[6];
  const float* elb = (const float*)d_in[7];
  const float* n1w = (const float*)d_in[8];
  const float* n1b = (const float*)d_in[9];
  const float* n2w = (const float*)d_in[10];
  const float* n2b = (const float*)d_in[11];
  const float* nlg = (const float*)d_in[12];
  const float* nlb = (const float*)d_in[13];
  const int* eidx = (const int*)d_in[14];
  float* x = (float*)d_out;

  char* p = (char*)d_ws;
  auto take = [&](size_t bytes) {
    char* r = p;
    p += (bytes + 255) & ~(size_t)255;
    return r;
  };
  short* efeat = (short*)take((size_t)NEDGE * DD * 2);  // sorted-order edge MLP out
  short* aggr = (short*)take((size_t)NNODE * DD * 2);
  short* xb = (short*)take((size_t)NNODE * DD * 2);     // bf16 mirror of x
  short* we1 = (short*)take((size_t)NLAY * DD * DD * 2);
  short* we2 = (short*)take((size_t)NLAY * DD * DD * 2);
  short* wn1 = (short*)take((size_t)NLAY * DD * DD * 2);
  short* wn2 = (short*)take((size_t)NLAY * DD * DD * 2);
  int* deg = (int*)take((size_t)NNODE * 4);
  int* offs = (int*)take((size_t)(NNODE + 1) * 4);
  int* cur = (int*)take((size_t)NNODE * 4);
  int* seid = (int*)take((size_t)NEDGE * 4);
  int* ssrc = (int*)take((size_t)NEDGE * 4);
  short* eab = (short*)take((size_t)NEDGE * DD * 2);    // sorted bf16 edge_attr
  const bool use_eab = ((size_t)(p - (char*)d_ws) <= ws_size);

  const int SMEM = 100352;
  hipFuncSetAttribute((const void*)mlp_kernel<true, false>,
                      hipFuncAttributeMaxDynamicSharedMemorySize, SMEM);
  hipFuncSetAttribute((const void*)mlp_kernel<false, false>,
                      hipFuncAttributeMaxDynamicSharedMemorySize, SMEM);
  hipFuncSetAttribute((const void*)mlp_kernel<true, true>,
                      hipFuncAttributeMaxDynamicSharedMemorySize, SMEM);

  hipMemcpyAsync(x, x_in, (size_t)NNODE * DD * 4, hipMemcpyDeviceToDevice, stream);

  const int wn4 = NLAY * DD * DD / 4;
  cvt4_kernel<<<576, 256, 0, stream>>>(e1w, we1, wn4);
  cvt4_kernel<<<576, 256, 0, stream>>>(e2w, we2, wn4);
  cvt4_kernel<<<576, 256, 0, stream>>>(n1w, wn1, wn4);
  cvt4_kernel<<<576, 256, 0, stream>>>(n2w, wn2, wn4);
  cvt4_kernel<<<2048, 256, 0, stream>>>(x_in, xb, NNODE * DD / 4);

  hipMemsetAsync(deg, 0, (size_t)NNODE * 4, stream);
  count_kernel<<<(NEDGE + 255) / 256, 256, 0, stream>>>(eidx + NEDGE, deg);
  scan_kernel<<<1, 1024, 0, stream>>>(deg, offs, cur);
  fill_kernel<<<(NEDGE + 255) / 256, 256, 0, stream>>>(eidx, eidx + NEDGE, cur, seid, ssrc);
  if (use_eab)
    gather_cvt_kernel<<<NEDGE / 4, 256, 0, stream>>>(ea_f, seid, eab, NEDGE);

  for (int l = 0; l < NLAY; ++l) {
    if (use_eab) {
      mlp_kernel<true, false><<<256, 256, SMEM, stream>>>(
          eab, nullptr, we1 + l * DD * DD, we2 + l * DD * DD, e1b + l * DD,
          e2b + l * DD, elg + l * DD, elb + l * DD, efeat, nullptr, nullptr,
          nullptr, NEDGE);
    } else {
      mlp_kernel<false, false><<<256, 256, SMEM, stream>>>(
          ea_f, seid, we1 + l * DD * DD, we2 + l * DD * DD, e1b + l * DD,
          e2b + l * DD, elg + l * DD, elb + l * DD, efeat, nullptr, nullptr,
          nullptr, NEDGE);
    }
    aggregate_kernel<<<(NNODE * 64 + 255) / 256, 256, 0, stream>>>(xb, efeat, offs, ssrc, aggr);
    mlp_kernel<true, true><<<256, 256, SMEM, stream>>>(
        aggr, nullptr, wn1 + l * DD * DD, wn2 + l * DD * DD, n1b + l * DD,
        n2b + l * DD, nlg + l * DD, nlb + l * DD, nullptr, x, x, xb, NNODE);
  }
  (void)in_sizes; (void)n_in; (void)out_size; (void)ws_size;
}

// Round 4
// 4775.250 us; speedup vs baseline: 1.6280x; 1.6280x over previous
//
#include <hip/hip_runtime.h>
#include <stdint.h>

#define DD 256
#define NEDGE 300000
#define NNODE 100000
#define NLAY 9
#define LN_EPS 1e-5f

typedef __attribute__((ext_vector_type(8))) short bf16x8;
typedef __attribute__((ext_vector_type(4))) short s16x4;
typedef __attribute__((ext_vector_type(4))) float f32x4;
typedef __attribute__((ext_vector_type(4))) int i32x4;

static __device__ __forceinline__ short f2bf(float f) {
  union { float f; uint32_t u; } v; v.f = f;
  uint32_t r = (v.u + 0x7FFFu + ((v.u >> 16) & 1u)) >> 16;
  return (short)(uint16_t)r;
}
static __device__ __forceinline__ float bf2f(short s) {
  union { uint32_t u; float f; } v; v.u = ((uint32_t)(uint16_t)s) << 16;
  return v.f;
}

// ---------------------------------------------------------------------------
// Fused MLP, register-direct operands. 256 thr = 4 waves; wave owns 64 cols.
// Per K-step each thread loads its 4 A-frags (global, line-reused across kk)
// and its 4 B-frags (global, L2-resident 128KB weights) straight to VGPRs.
// No LDS/barriers inside GEMMs; only the hidden handoff + LN sync per tile.
// ---------------------------------------------------------------------------
template<bool A_BF16, bool NODE>
__global__ __launch_bounds__(256, 2) void mlp_kernel(
    const void* __restrict__ Ain, const int* __restrict__ rowmap,
    const short* __restrict__ W1, const short* __restrict__ W2,
    const float* __restrict__ B1, const float* __restrict__ B2,
    const float* __restrict__ LG, const float* __restrict__ LB,
    short* __restrict__ OutB, float* __restrict__ OutF,
    const float* __restrict__ Resid, short* __restrict__ XbOut, int M) {
  __shared__ char smem[34816];
  short* hidden = (short*)smem;            // [64][256] bf16, granule-swizzled
  float* redbuf = (float*)(smem + 32768);  // LN cross-wave partials
  const int tid = threadIdx.x;
  const int lane = tid & 63;
  const int wv = tid >> 6;
  const int l15 = lane & 15, lq = lane >> 4;
  const int cbase = wv * 64;
  const int r0 = blockIdx.x * 64;

  // per-thread operand pointers
  const short* arow[4];
  const float* afrow[4];
#pragma unroll
  for (int mi = 0; mi < 4; ++mi) {
    const int ar = min(r0 + mi * 16 + l15, M - 1);
    if (A_BF16) arow[mi] = (const short*)Ain + (size_t)ar * DD + lq * 8;
    else        afrow[mi] = (const float*)Ain + (size_t)(rowmap ? rowmap[ar] : ar) * DD + lq * 8;
  }
  const short* wcol1[4];
  const short* wcol2[4];
  float b1v[4], b2v[4], gv[4], bvv[4];
#pragma unroll
  for (int ni = 0; ni < 4; ++ni) {
    const int c = cbase + ni * 16 + l15;
    wcol1[ni] = W1 + (size_t)c * DD + lq * 8;
    wcol2[ni] = W2 + (size_t)c * DD + lq * 8;
    b1v[ni] = B1[c]; b2v[ni] = B2[c]; gv[ni] = LG[c]; bvv[ni] = LB[c];
  }

  f32x4 acc[4][4];
#pragma unroll
  for (int mi = 0; mi < 4; ++mi)
#pragma unroll
    for (int ni = 0; ni < 4; ++ni) acc[mi][ni] = (f32x4){0.f, 0.f, 0.f, 0.f};

  // ---------------- GEMM1: h = relu(A @ W1^T + b1) — no barriers -----------
#pragma unroll
  for (int kk = 0; kk < 8; ++kk) {
    bf16x8 a[4], b[4];
#pragma unroll
    for (int mi = 0; mi < 4; ++mi) {
      if (A_BF16) {
        a[mi] = *(const bf16x8*)(arow[mi] + kk * 32);
      } else {
        const f32x4 u0 = *(const f32x4*)(afrow[mi] + kk * 32);
        const f32x4 u1 = *(const f32x4*)(afrow[mi] + kk * 32 + 4);
#pragma unroll
        for (int j = 0; j < 4; ++j) { a[mi][j] = f2bf(u0[j]); a[mi][j + 4] = f2bf(u1[j]); }
      }
    }
#pragma unroll
    for (int ni = 0; ni < 4; ++ni) b[ni] = *(const bf16x8*)(wcol1[ni] + kk * 32);
#pragma unroll
    for (int ni = 0; ni < 4; ++ni)
#pragma unroll
      for (int mi = 0; mi < 4; ++mi)
        acc[mi][ni] = __builtin_amdgcn_mfma_f32_16x16x32_bf16(a[mi], b[ni], acc[mi][ni], 0, 0, 0);
  }
  // epilogue 1: bias + relu -> hidden (granule-swizzled bf16)
#pragma unroll
  for (int ni = 0; ni < 4; ++ni) {
    const int c = cbase + ni * 16 + l15;
#pragma unroll
    for (int mi = 0; mi < 4; ++mi)
#pragma unroll
      for (int i = 0; i < 4; ++i) {
        const int row = mi * 16 + lq * 4 + i;
        hidden[row * DD + ((((c >> 3) ^ (row & 7))) << 3) + (c & 7)] =
            f2bf(fmaxf(acc[mi][ni][i] + b1v[ni], 0.f));
        acc[mi][ni][i] = 0.f;
      }
  }
  __syncthreads();  // hidden ready

  // ---------------- GEMM2: y = h @ W2^T — no barriers ----------------------
#pragma unroll
  for (int kk = 0; kk < 8; ++kk) {
    bf16x8 a[4], b[4];
#pragma unroll
    for (int mi = 0; mi < 4; ++mi) {
      const int hr = mi * 16 + l15;
      a[mi] = *(const bf16x8*)(hidden + hr * DD + (((kk * 4 + lq) ^ (hr & 7)) << 3));
    }
#pragma unroll
    for (int ni = 0; ni < 4; ++ni) b[ni] = *(const bf16x8*)(wcol2[ni] + kk * 32);
#pragma unroll
    for (int ni = 0; ni < 4; ++ni)
#pragma unroll
      for (int mi = 0; mi < 4; ++mi)
        acc[mi][ni] = __builtin_amdgcn_mfma_f32_16x16x32_bf16(a[mi], b[ni], acc[mi][ni], 0, 0, 0);
  }

  // ---------------- LayerNorm ----------------
  float mean_[4][4], inv_[4][4];
#pragma unroll
  for (int mi = 0; mi < 4; ++mi)
#pragma unroll
    for (int i = 0; i < 4; ++i) {
      float s1 = 0.f, s2 = 0.f;
#pragma unroll
      for (int ni = 0; ni < 4; ++ni) {
        const float v = acc[mi][ni][i] + b2v[ni];
        s1 += v; s2 += v * v;
      }
#pragma unroll
      for (int off = 1; off < 16; off <<= 1) {
        s1 += __shfl_xor(s1, off);
        s2 += __shfl_xor(s2, off);
      }
      mean_[mi][i] = s1; inv_[mi][i] = s2;
    }
  if (l15 == 0) {
#pragma unroll
    for (int mi = 0; mi < 4; ++mi)
#pragma unroll
      for (int i = 0; i < 4; ++i) {
        const int row = mi * 16 + lq * 4 + i;
        redbuf[(row * 4 + wv) * 2 + 0] = mean_[mi][i];
        redbuf[(row * 4 + wv) * 2 + 1] = inv_[mi][i];
      }
  }
  __syncthreads();  // redbuf ready; hidden reads complete
#pragma unroll
  for (int mi = 0; mi < 4; ++mi)
#pragma unroll
    for (int i = 0; i < 4; ++i) {
      const int row = mi * 16 + lq * 4 + i;
      float t1 = 0.f, t2 = 0.f;
#pragma unroll
      for (int w = 0; w < 4; ++w) {
        t1 += redbuf[(row * 4 + w) * 2 + 0];
        t2 += redbuf[(row * 4 + w) * 2 + 1];
      }
      const float mean = t1 * (1.f / 256.f);
      const float var = t2 * (1.f / 256.f) - mean * mean;
      mean_[mi][i] = mean;
      inv_[mi][i] = rsqrtf(var + LN_EPS);
    }

  if (NODE) {
    // two passes of 128 cols through the 32KB smem region (f32)
    float* ob = (float*)smem;
#pragma unroll
    for (int h = 0; h < 2; ++h) {
      if ((cbase >> 7) == h) {
#pragma unroll
        for (int ni = 0; ni < 4; ++ni) {
          const int cl = cbase - h * 128 + ni * 16 + l15;
#pragma unroll
          for (int mi = 0; mi < 4; ++mi)
#pragma unroll
            for (int i = 0; i < 4; ++i) {
              const int row = mi * 16 + lq * 4 + i;
              const float y = (acc[mi][ni][i] + b2v[ni] - mean_[mi][i]) * inv_[mi][i] * gv[ni] + bvv[ni];
              ob[row * 128 + (((cl >> 2) ^ (row & 7)) << 2) + (cl & 3)] = y;
            }
        }
      }
      __syncthreads();  // ob(h) ready
#pragma unroll
      for (int j = 0; j < 8; ++j) {
        const int gg = tid + 256 * j;
        const int row = gg >> 5, Lc = gg & 31;
        const int grow = r0 + row;
        if (grow < M) {
          f32x4 v = *(const f32x4*)(ob + row * 128 + ((Lc ^ (row & 7)) << 2));
          const f32x4 xr = *(const f32x4*)(Resid + (size_t)grow * DD + h * 128 + Lc * 4);
          v = v + xr;
          *(f32x4*)(OutF + (size_t)grow * DD + h * 128 + Lc * 4) = v;
          s16x4 o; o.x = f2bf(v.x); o.y = f2bf(v.y); o.z = f2bf(v.z); o.w = f2bf(v.w);
          *(s16x4*)(XbOut + (size_t)grow * DD + h * 128 + Lc * 4) = o;
        }
      }
      if (h == 0) __syncthreads();  // ob reads done before pass 1 writes
    }
  } else {
    short* ob = hidden;  // reuse region, same swizzle
#pragma unroll
    for (int ni = 0; ni < 4; ++ni) {
      const int c = cbase + ni * 16 + l15;
#pragma unroll
      for (int mi = 0; mi < 4; ++mi)
#pragma unroll
        for (int i = 0; i < 4; ++i) {
          const int row = mi * 16 + lq * 4 + i;
          const float y = (acc[mi][ni][i] + b2v[ni] - mean_[mi][i]) * inv_[mi][i] * gv[ni] + bvv[ni];
          ob[row * DD + (((c >> 3) ^ (row & 7)) << 3) + (c & 7)] = f2bf(y);
        }
    }
    __syncthreads();  // ob ready
#pragma unroll
    for (int j = 0; j < 8; ++j) {
      const int gg = tid + 256 * j;
      const int row = gg >> 5, Lg = gg & 31;
      const int grow = r0 + row;
      if (grow < M) {
        const i32x4 v = *(const i32x4*)(ob + row * DD + ((Lg ^ (row & 7)) << 3));
        *(i32x4*)(OutB + (size_t)grow * DD + Lg * 8) = v;
      }
    }
  }
}

// ----------------------- aggregation: wave per node, CSR-sorted efeat ------
__global__ __launch_bounds__(256) void aggregate_kernel(
    const short* __restrict__ xb, const short* __restrict__ efs,
    const int* __restrict__ offs, const int* __restrict__ ssrc,
    short* __restrict__ aggr) {
  const int w = (blockIdx.x * blockDim.x + threadIdx.x) >> 6;
  if (w >= NNODE) return;
  const int lane = threadIdx.x & 63;
  const int beg = offs[w], end = offs[w + 1];
  float s0 = 0.f, s1 = 0.f, s2 = 0.f, s3 = 0.f;
  int p = beg;
  for (; p + 3 < end; p += 4) {
    const int a0 = ssrc[p], a1 = ssrc[p + 1], a2 = ssrc[p + 2], a3 = ssrc[p + 3];
    const s16x4 e0 = *(const s16x4*)(efs + (size_t)p * DD + lane * 4);
    const s16x4 e1 = *(const s16x4*)(efs + (size_t)(p + 1) * DD + lane * 4);
    const s16x4 e2 = *(const s16x4*)(efs + (size_t)(p + 2) * DD + lane * 4);
    const s16x4 e3 = *(const s16x4*)(efs + (size_t)(p + 3) * DD + lane * 4);
    const s16x4 x0 = *(const s16x4*)(xb + (size_t)a0 * DD + lane * 4);
    const s16x4 x1 = *(const s16x4*)(xb + (size_t)a1 * DD + lane * 4);
    const s16x4 x2 = *(const s16x4*)(xb + (size_t)a2 * DD + lane * 4);
    const s16x4 x3 = *(const s16x4*)(xb + (size_t)a3 * DD + lane * 4);
    s0 += bf2f(e0.x) + bf2f(x0.x) + bf2f(e1.x) + bf2f(x1.x) +
          bf2f(e2.x) + bf2f(x2.x) + bf2f(e3.x) + bf2f(x3.x);
    s1 += bf2f(e0.y) + bf2f(x0.y) + bf2f(e1.y) + bf2f(x1.y) +
          bf2f(e2.y) + bf2f(x2.y) + bf2f(e3.y) + bf2f(x3.y);
    s2 += bf2f(e0.z) + bf2f(x0.z) + bf2f(e1.z) + bf2f(x1.z) +
          bf2f(e2.z) + bf2f(x2.z) + bf2f(e3.z) + bf2f(x3.z);
    s3 += bf2f(e0.w) + bf2f(x0.w) + bf2f(e1.w) + bf2f(x1.w) +
          bf2f(e2.w) + bf2f(x2.w) + bf2f(e3.w) + bf2f(x3.w);
  }
  for (; p < end; ++p) {
    const s16x4 ev = *(const s16x4*)(efs + (size_t)p * DD + lane * 4);
    const s16x4 xv = *(const s16x4*)(xb + (size_t)ssrc[p] * DD + lane * 4);
    s0 += bf2f(ev.x) + bf2f(xv.x);
    s1 += bf2f(ev.y) + bf2f(xv.y);
    s2 += bf2f(ev.z) + bf2f(xv.z);
    s3 += bf2f(ev.w) + bf2f(xv.w);
  }
  s16x4 o; o.x = f2bf(s0); o.y = f2bf(s1); o.z = f2bf(s2); o.w = f2bf(s3);
  *(s16x4*)(aggr + (size_t)w * DD + lane * 4) = o;
}

__global__ void count_kernel(const int* __restrict__ tgt, int* __restrict__ deg) {
  const int e = blockIdx.x * 256 + threadIdx.x;
  if (e < NEDGE) atomicAdd(&deg[tgt[e]], 1);
}

__global__ __launch_bounds__(1024) void scan_kernel(
    const int* __restrict__ deg, int* __restrict__ offs, int* __restrict__ cur) {
  __shared__ int part[1024];
  const int t = threadIdx.x;
  const int CH = 98;  // 1024*98 >= 100000
  const int base = t * CH;
  int s = 0;
  for (int i = 0; i < CH; ++i) {
    const int idx = base + i;
    if (idx < NNODE) s += deg[idx];
  }
  part[t] = s;
  __syncthreads();
  for (int off = 1; off < 1024; off <<= 1) {
    const int v = (t >= off) ? part[t - off] : 0;
    __syncthreads();
    part[t] += v;
    __syncthreads();
  }
  int run = (t > 0) ? part[t - 1] : 0;  // exclusive prefix
  for (int i = 0; i < CH; ++i) {
    const int idx = base + i;
    if (idx < NNODE) {
      offs[idx] = run;
      cur[idx] = run;
      run += deg[idx];
    }
  }
  if (t == 1023) offs[NNODE] = part[1023];
}

__global__ void fill_kernel(const int* __restrict__ src, const int* __restrict__ tgt,
                            int* cur, int* seid, int* ssrc) {
  const int e = blockIdx.x * 256 + threadIdx.x;
  if (e < NEDGE) {
    const int t = tgt[e];
    const int p = atomicAdd(&cur[t], 1);
    seid[p] = e;
    ssrc[p] = src[e];
  }
}

__global__ void cvt4_kernel(const float* __restrict__ src, short* __restrict__ dst, int n4) {
  for (int i = blockIdx.x * blockDim.x + threadIdx.x; i < n4; i += gridDim.x * blockDim.x) {
    const f32x4 v = ((const f32x4*)src)[i];
    s16x4 o;
    o.x = f2bf(v.x); o.y = f2bf(v.y); o.z = f2bf(v.z); o.w = f2bf(v.w);
    ((s16x4*)dst)[i] = o;
  }
}

// gather rows by perm and convert f32 -> bf16 (wave per row)
__global__ __launch_bounds__(256) void gather_cvt_kernel(
    const float* __restrict__ src, const int* __restrict__ perm,
    short* __restrict__ dst, int n) {
  const int w = (blockIdx.x * blockDim.x + threadIdx.x) >> 6;
  if (w >= n) return;
  const int lane = threadIdx.x & 63;
  const f32x4 v = *(const f32x4*)(src + (size_t)perm[w] * DD + lane * 4);
  s16x4 o; o.x = f2bf(v.x); o.y = f2bf(v.y); o.z = f2bf(v.z); o.w = f2bf(v.w);
  *(s16x4*)(dst + (size_t)w * DD + lane * 4) = o;
}

// ---------------------------------------------------------------------------
extern "C" void kernel_launch(void* const* d_in, const int* in_sizes, int n_in,
                              void* d_out, int out_size, void* d_ws, size_t ws_size,
                              hipStream_t stream) {
  const float* x_in = (const float*)d_in[0];
  const float* ea_f = (const float*)d_in[1];
  const float* e1w = (const float*)d_in[2];
  const float* e1b = (const float*)d_in[3];
  const float* e2w = (const float*)d_in[4];
  const float* e2b = (const float*)d_in[5];
  const float* elg = (const float*)d_in[6];
  const float* elb = (const float*)d_in[7];
  const float* n1w = (const float*)d_in[8];
  const float* n1b = (const float*)d_in[9];
  const float* n2w = (const float*)d_in[10];
  const float* n2b = (const float*)d_in[11];
  const float* nlg = (const float*)d_in[12];
  const float* nlb = (const float*)d_in[13];
  const int* eidx = (const int*)d_in[14];
  float* x = (float*)d_out;

  char* p = (char*)d_ws;
  auto take = [&](size_t bytes) {
    char* r = p;
    p += (bytes + 255) & ~(size_t)255;
    return r;
  };
  short* efeat = (short*)take((size_t)NEDGE * DD * 2);  // sorted-order edge MLP out
  short* aggr = (short*)take((size_t)NNODE * DD * 2);
  short* xb = (short*)take((size_t)NNODE * DD * 2);     // bf16 mirror of x
  short* we1 = (short*)take((size_t)NLAY * DD * DD * 2);
  short* we2 = (short*)take((size_t)NLAY * DD * DD * 2);
  short* wn1 = (short*)take((size_t)NLAY * DD * DD * 2);
  short* wn2 = (short*)take((size_t)NLAY * DD * DD * 2);
  int* deg = (int*)take((size_t)NNODE * 4);
  int* offs = (int*)take((size_t)(NNODE + 1) * 4);
  int* cur = (int*)take((size_t)NNODE * 4);
  int* seid = (int*)take((size_t)NEDGE * 4);
  int* ssrc = (int*)take((size_t)NEDGE * 4);
  short* eab = (short*)take((size_t)NEDGE * DD * 2);    // sorted bf16 edge_attr
  const bool use_eab = ((size_t)(p - (char*)d_ws) <= ws_size);

  hipMemcpyAsync(x, x_in, (size_t)NNODE * DD * 4, hipMemcpyDeviceToDevice, stream);

  const int wn4 = NLAY * DD * DD / 4;
  cvt4_kernel<<<576, 256, 0, stream>>>(e1w, we1, wn4);
  cvt4_kernel<<<576, 256, 0, stream>>>(e2w, we2, wn4);
  cvt4_kernel<<<576, 256, 0, stream>>>(n1w, wn1, wn4);
  cvt4_kernel<<<576, 256, 0, stream>>>(n2w, wn2, wn4);
  cvt4_kernel<<<2048, 256, 0, stream>>>(x_in, xb, NNODE * DD / 4);

  hipMemsetAsync(deg, 0, (size_t)NNODE * 4, stream);
  count_kernel<<<(NEDGE + 255) / 256, 256, 0, stream>>>(eidx + NEDGE, deg);
  scan_kernel<<<1, 1024, 0, stream>>>(deg, offs, cur);
  fill_kernel<<<(NEDGE + 255) / 256, 256, 0, stream>>>(eidx, eidx + NEDGE, cur, seid, ssrc);
  if (use_eab)
    gather_cvt_kernel<<<NEDGE / 4, 256, 0, stream>>>(ea_f, seid, eab, NEDGE);

  const int egrid = (NEDGE + 63) / 64;
  const int ngrid = (NNODE + 63) / 64;
  for (int l = 0; l < NLAY; ++l) {
    if (use_eab) {
      mlp_kernel<true, false><<<egrid, 256, 0, stream>>>(
          eab, nullptr, we1 + l * DD * DD, we2 + l * DD * DD, e1b + l * DD,
          e2b + l * DD, elg + l * DD, elb + l * DD, efeat, nullptr, nullptr,
          nullptr, NEDGE);
    } else {
      mlp_kernel<false, false><<<egrid, 256, 0, stream>>>(
          ea_f, seid, we1 + l * DD * DD, we2 + l * DD * DD, e1b + l * DD,
          e2b + l * DD, elg + l * DD, elb + l * DD, efeat, nullptr, nullptr,
          nullptr, NEDGE);
    }
    aggregate_kernel<<<(NNODE * 64 + 255) / 256, 256, 0, stream>>>(xb, efeat, offs, ssrc, aggr);
    mlp_kernel<true, true><<<ngrid, 256, 0, stream>>>(
        aggr, nullptr, wn1 + l * DD * DD, wn2 + l * DD * DD, n1b + l * DD,
        n2b + l * DD, nlg + l * DD, nlb + l * DD, nullptr, x, x, xb, NNODE);
  }
  (void)in_sizes; (void)n_in; (void)out_size; (void)ws_size;
}